// Round 7
// baseline (3066.139 us; speedup 1.0000x reference)
//
#include <hip/hip_runtime.h>
#include <stdint.h>

#define L_ 512
#define NBUF (L_ * L_)
#define T_ 64
#define NT_ 8
#define INFV 3.0e38f

// ---------------------------------------------------------------------------
// pair_mask dtype probe (unchanged from r5/r6 — verified working).
// ---------------------------------------------------------------------------
__global__ __launch_bounds__(1024) void fd_mask_probe(const unsigned int* __restrict__ pm,
                                                      int n32,
                                                      unsigned int* __restrict__ flags) {
    __shared__ unsigned int sf;
    if (threadIdx.x == 0) sf = 0u;
    __syncthreads();
    unsigned int local = 0;
    const int nscan = n32 < 65536 ? n32 : 65536;
    for (int idx = threadIdx.x; idx < nscan; idx += 1024) {
        const unsigned int w = pm[idx];
        const unsigned int h0 = w & 0xFFFFu, h1 = w >> 16;
        if (w > 1u) local |= 1u;
        if (w & 0xFEFEFEFEu) local |= 2u;
        if ((h0 != 0u && h0 != 0x3F80u) || (h1 != 0u && h1 != 0x3F80u)) local |= 4u;
        if (w == 0x3F803F80u || w == 0x00003F80u) local |= 8u;
        if ((h0 != 0u && h0 != 0x3C00u) || (h1 != 0u && h1 != 0x3C00u)) local |= 16u;
    }
    if (local) atomicOr(&sf, local);
    __syncthreads();
    if (threadIdx.x == 0) flags[0] = sf;
}

__device__ __forceinline__ int mask_mode(unsigned int f) {
    if (!(f & 1u)) return 0;                 // int32 0/1
    if (!(f & 2u)) return 1;                 // uint8 0/1
    if (!(f & 4u)) return (f & 8u) ? 3 : 2;  // bf16 vs f32
    return (!(f & 16u)) ? 3 : 2;             // f16 else f32
}

__device__ __forceinline__ bool mask_bit(int mode, const unsigned int* pmW,
                                         const unsigned char* pm8,
                                         const unsigned short* pm16,
                                         const float* pmf, size_t gi) {
    if (mode == 0) return pmW[gi] != 0u;
    if (mode == 1) return pm8[gi] != 0;
    if (mode == 3) return pm16[gi] != 0;
    return pmf[gi] != 0.0f;
}

// ---------------------------------------------------------------------------
// Diagonal tiles (d=0): triangular 64x64 DP fully in LDS (r6-verified).
// ---------------------------------------------------------------------------
__global__ __launch_bounds__(256) void fd_diag(
    const float* __restrict__ e_pair, const float* __restrict__ e_unp,
    const unsigned int* __restrict__ pm, const unsigned int* __restrict__ flags,
    float* __restrict__ dp_ws, unsigned short* __restrict__ ptr_ws)
{
    const int b = blockIdx.x / NT_;
    const int I = blockIdx.x % NT_;
    const int t = threadIdx.x;
    const int r0 = I * T_;
    const float* ep = e_pair + (size_t)b * NBUF;
    float* dp = dp_ws + (size_t)b * NBUF;
    unsigned short* ptr = ptr_ws + (size_t)b * NBUF;
    const int mode = mask_mode(flags[0]);
    const unsigned int*   pmW  = pm + (size_t)b * NBUF;
    const unsigned char*  pm8  = ((const unsigned char*) pm) + (size_t)b * NBUF;
    const unsigned short* pm16 = ((const unsigned short*)pm) + (size_t)b * NBUF;
    const float*          pmf  = ((const float*)         pm) + (size_t)b * NBUF;

    __shared__ float Ct[T_][T_ + 4];
    __shared__ float epl[T_][T_ + 4];
    __shared__ unsigned char mkb[T_][T_ + 4];
    __shared__ unsigned short bp[T_][T_ + 4];
    __shared__ float eu[T_];

    for (int e = t; e < T_ * T_; e += 256) {
        const int r = e >> 6, c = e & 63;
        const size_t gi = (size_t)(r0 + r) * L_ + r0 + c;
        epl[r][c] = ep[gi];
        mkb[r][c] = mask_bit(mode, pmW, pm8, pm16, pmf, gi) ? 1 : 0;
    }
    if (t < T_) eu[t] = e_unp[(size_t)b * L_ + r0 + t];
    __syncthreads();
    if (t < T_) Ct[t][t] = eu[t];
    __syncthreads();

    const int cell = t >> 2, sub = t & 3;
    for (int m = 1; m < T_; ++m) {
        if (cell < T_ - m) {
            const int ti = cell, tj = cell + m;
            float mv = INFV; int km = 0;
            for (int tk = ti + sub; tk < tj; tk += 4) {
                const float v = Ct[ti][tk] + Ct[tk + 1][tj];
                if (v < mv) { mv = v; km = tk; }
            }
            for (int off = 1; off < 4; off <<= 1) {
                const float ov = __shfl_xor(mv, off, 4);
                const int   ok = __shfl_xor(km, off, 4);
                if (ov < mv || (ov == mv && ok < km)) { mv = ov; km = ok; }
            }
            if (sub == 0) {
                const float c0 = Ct[ti + 1][tj] + eu[ti];
                const float c1 = Ct[ti][tj - 1] + eu[tj];
                const float inner = (m >= 2) ? Ct[ti + 1][tj - 1] : 0.0f;
                const float c2 = inner + epl[ti][tj];
                const bool pok = mkb[ti][tj] && (m > 4);
                float best = c0; int bv = 0;
                if (c1 < best)        { best = c1; bv = 1; }
                if (pok && c2 < best) { best = c2; bv = 2; }
                if (mv < best)        { best = mv; bv = r0 + km + 3; }
                Ct[ti][tj] = best;
                bp[ti][tj] = (unsigned short)bv;
            }
        }
        __syncthreads();
    }
    for (int e = t; e < T_ * T_; e += 256) {
        const int r = e >> 6, c = e & 63;
        if (c >= r) {
            const size_t gi = (size_t)(r0 + r) * L_ + r0 + c;
            dp[gi] = Ct[r][c];
            if (c > r) ptr[gi] = bp[r][c];
        }
    }
}

// ---------------------------------------------------------------------------
// Off-diagonal tile step (d>=1). Bulk min-plus over interior K blocks
// (4x4 reg tiles, as r6) then a 127-step intra-tile wavefront with ONE
// thread per cell: shuffle-free, 4-accumulator interleaved k-loops,
// explicit lex-(v,k) merges (== numpy first-occurrence argmin).
// Column accesses are made row-contiguous via CtT and transposed (J,J).
// ---------------------------------------------------------------------------
__global__ __launch_bounds__(256) void fd_step(
    const float* __restrict__ e_pair, const float* __restrict__ e_unp,
    const unsigned int* __restrict__ pm, const unsigned int* __restrict__ flags,
    float* __restrict__ dp_ws, unsigned short* __restrict__ ptr_ws,
    int d, int nI)
{
    const int b = blockIdx.x / nI;
    const int I = blockIdx.x % nI;
    const int J = I + d;
    const int t = threadIdx.x;
    const int r0 = I * T_, q0 = J * T_;
    const float* ep = e_pair + (size_t)b * NBUF;
    float* dp = dp_ws + (size_t)b * NBUF;
    unsigned short* ptr = ptr_ws + (size_t)b * NBUF;
    const int mode = mask_mode(flags[0]);
    const unsigned int*   pmW  = pm + (size_t)b * NBUF;
    const unsigned char*  pm8  = ((const unsigned char*) pm) + (size_t)b * NBUF;
    const unsigned short* pm16 = ((const unsigned short*)pm) + (size_t)b * NBUF;
    const float*          pmf  = ((const float*)         pm) + (size_t)b * NBUF;

    __shared__ float SA[T_][T_ + 4];    // bulk: dp[i][k] rows; wavefront: tile (I,I) row-major
    __shared__ float SBX[T_][T_ + 4];   // bulk: dp[k+1][j] rows; wavefront: tile (J,J) TRANSPOSED
    __shared__ float Ct[T_][T_ + 4];    // tile being computed, row-major
    __shared__ float CtT[T_][T_ + 4];   // transposed copy (column reads -> row reads)
    __shared__ float accv[T_][T_ + 4];
    __shared__ unsigned short acck[T_][T_ + 4];
    __shared__ float epl[T_][T_ + 4];
    __shared__ unsigned char mkb[T_][T_ + 4];
    __shared__ unsigned short bp[T_][T_ + 4];
    __shared__ float euI[T_], euJ[T_], rowB[T_], colL[T_];
    __shared__ float cornerS;

    // ---- bulk: k in [(I+1)T, JT) ----
    if (d >= 2) {
        float av[16]; int akr[16];
        const int ti0 = (t >> 4) * 4, tj0 = (t & 15) * 4;
#pragma unroll
        for (int q = 0; q < 16; ++q) { av[q] = INFV; akr[q] = 0; }
        for (int K = I + 1; K < J; ++K) {
            const int kb = K * T_;
            __syncthreads();
            for (int e = t; e < T_ * T_ / 4; e += 256) {
                const int r = e >> 4, c4 = (e & 15) * 4;
                *(float4*)&SA[r][c4]  = *(const float4*)&dp[(size_t)(r0 + r) * L_ + kb + c4];
                *(float4*)&SBX[r][c4] = *(const float4*)&dp[(size_t)(kb + 1 + r) * L_ + q0 + c4];
            }
            __syncthreads();
            for (int kk = 0; kk < T_; ++kk) {
                float a[4], bb[4];
#pragma unroll
                for (int r = 0; r < 4; ++r) a[r] = SA[ti0 + r][kk];
#pragma unroll
                for (int c = 0; c < 4; ++c) bb[c] = SBX[kk][tj0 + c];
                const int kg = kb + kk;
#pragma unroll
                for (int r = 0; r < 4; ++r)
#pragma unroll
                    for (int c = 0; c < 4; ++c) {
                        const float v = a[r] + bb[c];
                        const int q = r * 4 + c;
                        if (v < av[q]) { av[q] = v; akr[q] = kg; }   // ascending k
                    }
            }
        }
#pragma unroll
        for (int r = 0; r < 4; ++r)
#pragma unroll
            for (int c = 0; c < 4; ++c) {
                accv[ti0 + r][tj0 + c] = av[r * 4 + c];
                acck[ti0 + r][tj0 + c] = (unsigned short)akr[r * 4 + c];
            }
    }
    __syncthreads();   // protect SA/SBX restage

    // ---- stage wavefront inputs ----
    for (int e = t; e < T_ * T_ / 4; e += 256) {
        const int r = e >> 4, c4 = (e & 15) * 4;
        *(float4*)&SA[r][c4]  = *(const float4*)&dp[(size_t)(r0 + r) * L_ + r0 + c4];  // (I,I)
        const float4 vj = *(const float4*)&dp[(size_t)(q0 + r) * L_ + q0 + c4];        // (J,J) row
        SBX[c4 + 0][r] = vj.x; SBX[c4 + 1][r] = vj.y;                                  // transpose
        SBX[c4 + 2][r] = vj.z; SBX[c4 + 3][r] = vj.w;
        *(float4*)&epl[r][c4] = *(const float4*)&ep[(size_t)(r0 + r) * L_ + q0 + c4];
    }
    for (int e = t; e < T_ * T_; e += 256) {
        const int r = e >> 6, c = e & 63;
        mkb[r][c] = mask_bit(mode, pmW, pm8, pm16, pmf, (size_t)(r0 + r) * L_ + q0 + c) ? 1 : 0;
    }
    if (t < T_) {
        euI[t] = e_unp[(size_t)b * L_ + r0 + t];
        euJ[t] = e_unp[(size_t)b * L_ + q0 + t];
        rowB[t] = dp[(size_t)(r0 + T_) * L_ + q0 + t];   // dp[(I+1)T][j]
        colL[t] = dp[(size_t)(r0 + t) * L_ + q0 - 1];    // dp[i][JT-1]
    }
    if (t == 0) cornerS = (d >= 2) ? dp[(size_t)(r0 + T_) * L_ + q0 - 1] : 0.0f;
    __syncthreads();

    // ---- intra-tile wavefront: one thread per cell, shuffle-free ----
    for (int m = -(T_ - 1); m <= T_ - 1; ++m) {
        const int am = m < 0 ? -m : m;
        const int ncell = T_ - am;
        if (t < ncell) {
            const int ti = (m < 0) ? t + am : t;
            const int tj = ti + m;
            const int span = d * T_ + m;
            float v0 = INFV, v1 = INFV, v2 = INFV, v3 = INFV;
            int   k0 = 0,    k1 = 0,    k2 = 0,    k3 = 0;
            // left part: k = r0+tk, tk in [ti, T)
            int tk = ti;
            for (; tk + 4 <= T_ - 1; tk += 4) {
                const float x0 = SA[ti][tk + 0] + CtT[tj][tk + 1];
                const float x1 = SA[ti][tk + 1] + CtT[tj][tk + 2];
                const float x2 = SA[ti][tk + 2] + CtT[tj][tk + 3];
                const float x3 = SA[ti][tk + 3] + CtT[tj][tk + 4];
                if (x0 < v0) { v0 = x0; k0 = r0 + tk + 0; }
                if (x1 < v1) { v1 = x1; k1 = r0 + tk + 1; }
                if (x2 < v2) { v2 = x2; k2 = r0 + tk + 2; }
                if (x3 < v3) { v3 = x3; k3 = r0 + tk + 3; }
            }
            for (; tk < T_ - 1; ++tk) {
                const float x = SA[ti][tk] + CtT[tj][tk + 1];
                if (x < v0) { v0 = x; k0 = r0 + tk; }
            }
            { const float x = SA[ti][T_ - 1] + rowB[tj];         // tk = T-1
              if (x < v1) { v1 = x; k1 = r0 + T_ - 1; } }
            // right part: k = q0+tk, tk in [0, tj)  (all ks > left ks)
            tk = 0;
            for (; tk + 4 <= tj; tk += 4) {
                const float x0 = Ct[ti][tk + 0] + SBX[tj][tk + 1];
                const float x1 = Ct[ti][tk + 1] + SBX[tj][tk + 2];
                const float x2 = Ct[ti][tk + 2] + SBX[tj][tk + 3];
                const float x3 = Ct[ti][tk + 3] + SBX[tj][tk + 4];
                if (x0 < v0) { v0 = x0; k0 = q0 + tk + 0; }
                if (x1 < v1) { v1 = x1; k1 = q0 + tk + 1; }
                if (x2 < v2) { v2 = x2; k2 = q0 + tk + 2; }
                if (x3 < v3) { v3 = x3; k3 = q0 + tk + 3; }
            }
            for (; tk < tj; ++tk) {
                const float x = Ct[ti][tk] + SBX[tj][tk + 1];
                if (x < v2) { v2 = x; k2 = q0 + tk; }
            }
            // lex-(v,k) merges (first-occurrence over ascending k)
            float mv = v0; int km = k0;
            if (v1 < mv || (v1 == mv && k1 < km)) { mv = v1; km = k1; }
            if (v2 < mv || (v2 == mv && k2 < km)) { mv = v2; km = k2; }
            if (v3 < mv || (v3 == mv && k3 < km)) { mv = v3; km = k3; }
            if (d >= 2) {
                const float bv = accv[ti][tj]; const int bk = acck[ti][tj];
                if (bv < mv || (bv == mv && bk < km)) { mv = bv; km = bk; }
            }
            const float c0 = ((ti < T_ - 1) ? Ct[ti + 1][tj] : rowB[tj]) + euI[ti];
            const float c1 = ((tj > 0) ? Ct[ti][tj - 1] : colL[ti]) + euJ[tj];
            float inner;
            if (span == 1)        inner = 0.0f;
            else if (ti < T_ - 1) inner = (tj > 0) ? Ct[ti + 1][tj - 1] : colL[ti + 1];
            else                  inner = (tj > 0) ? rowB[tj - 1] : cornerS;
            const float c2 = inner + epl[ti][tj];
            const bool pok = mkb[ti][tj] && (span > 4);
            float best = c0; int bv2 = 0;
            if (c1 < best)        { best = c1; bv2 = 1; }
            if (pok && c2 < best) { best = c2; bv2 = 2; }
            if (mv < best)        { best = mv; bv2 = km + 3; }
            Ct[ti][tj] = best;
            CtT[tj][ti] = best;
            bp[ti][tj] = (unsigned short)bv2;
        }
        __syncthreads();
    }

    // ---- writeback ----
    for (int e = t; e < T_ * T_ / 4; e += 256) {
        const int r = e >> 4, c4 = (e & 15) * 4;
        *(float4*)&dp[(size_t)(r0 + r) * L_ + q0 + c4] = *(const float4*)&Ct[r][c4];
    }
    for (int e = t; e < T_ * T_; e += 256) {
        const int r = e >> 6, c = e & 63;
        ptr[(size_t)(r0 + r) * L_ + q0 + c] = bp[r][c];
    }
}

// ---------------------------------------------------------------------------
// Backtrace: one block per batch. Phase 1 warms this batch's 512KB ptr
// table into the local XCD's L2 (dirty lines from other XCDs otherwise cost
// ~900cyc/pop on the serial chain). Phase 2: serial LIFO walk (t==0), L2-hit.
// ---------------------------------------------------------------------------
__global__ __launch_bounds__(256) void fd_backtrace(
    const unsigned short* __restrict__ ptr_ws, int* __restrict__ out)
{
    const int b = blockIdx.x;
    const int t = threadIdx.x;
    const unsigned short* ptr = ptr_ws + (size_t)b * NBUF;
    int* res = out + (size_t)b * L_;
    __shared__ int sti[2 * L_], stj[2 * L_];

    const uint4* p4 = (const uint4*)ptr;           // 512KB = 32768 uint4
    unsigned int acc = 0;
    for (int idx = t; idx < NBUF / 8; idx += 256) {
        const uint4 v = p4[idx];
        acc += v.x ^ v.y ^ v.z ^ v.w;
    }
    asm volatile("" :: "v"(acc));                  // keep warm loads live
    for (int idx = t; idx < L_; idx += 256) res[idx] = -1;
    __syncthreads();

    if (t == 0) {
        int sp = 1; sti[0] = 0; stj[0] = L_ - 1;
        while (sp > 0) {
            --sp;
            const int i = sti[sp], j = stj[sp];
            if (i < j) {
                const int p = (int)ptr[(size_t)i * L_ + j];
                if (p == 0)      { sti[sp] = i + 1; stj[sp] = j;     ++sp; }
                else if (p == 1) { sti[sp] = i;     stj[sp] = j - 1; ++sp; }
                else if (p == 2) {
                    res[i] = j; res[j] = i;
                    if (i + 1 <= j - 1) { sti[sp] = i + 1; stj[sp] = j - 1; ++sp; }
                } else {
                    const int k = p - 3;
                    sti[sp] = i;     stj[sp] = k; ++sp;   // pushed first
                    sti[sp] = k + 1; stj[sp] = j; ++sp;   // popped first (matches ref)
                }
            }
        }
    }
}

extern "C" void kernel_launch(void* const* d_in, const int* in_sizes, int n_in,
                              void* d_out, int out_size, void* d_ws, size_t ws_size,
                              hipStream_t stream) {
    const float* e_pair = (const float*)d_in[0];
    const float* e_unp  = (const float*)d_in[1];
    const unsigned int* pm = (const unsigned int*)d_in[2];
    const int B = in_sizes[1] / L_;
    int* out = (int*)d_out;

    // ws layout: [flags: 256B] [dp: B*L*L f32] [ptr: B*L*L u16]
    unsigned int* flags = (unsigned int*)d_ws;
    float* dp_ws = (float*)((char*)d_ws + 256);
    unsigned short* ptr_ws = (unsigned short*)(dp_ws + (size_t)B * NBUF);

    const int n32 = in_sizes[2] / 4;
    fd_mask_probe<<<dim3(1), dim3(1024), 0, stream>>>(pm, n32, flags);
    fd_diag<<<dim3(B * NT_), dim3(256), 0, stream>>>(e_pair, e_unp, pm, flags,
                                                     dp_ws, ptr_ws);
    for (int d = 1; d < NT_; ++d) {
        const int nI = NT_ - d;
        fd_step<<<dim3(B * nI), dim3(256), 0, stream>>>(e_pair, e_unp, pm, flags,
                                                        dp_ws, ptr_ws, d, nI);
    }
    fd_backtrace<<<dim3(B), dim3(256), 0, stream>>>(ptr_ws, out);
}

// Round 8
// 2228.018 us; speedup vs baseline: 1.3762x; 1.3762x over previous
//
#include <hip/hip_runtime.h>
#include <stdint.h>

#define L_ 512
#define NBUF (L_ * L_)
#define T_ 64
#define NT_ 8
#define PAD 5              // row stride 69: 69%32=5, gcd(5,32)=1 -> <=2-way banks everywhere
#define INFV 3.0e38f

// ---------------------------------------------------------------------------
// pair_mask dtype probe (unchanged since r5 — verified working).
// ---------------------------------------------------------------------------
__global__ __launch_bounds__(1024) void fd_mask_probe(const unsigned int* __restrict__ pm,
                                                      int n32,
                                                      unsigned int* __restrict__ flags) {
    __shared__ unsigned int sf;
    if (threadIdx.x == 0) sf = 0u;
    __syncthreads();
    unsigned int local = 0;
    const int nscan = n32 < 65536 ? n32 : 65536;
    for (int idx = threadIdx.x; idx < nscan; idx += 1024) {
        const unsigned int w = pm[idx];
        const unsigned int h0 = w & 0xFFFFu, h1 = w >> 16;
        if (w > 1u) local |= 1u;
        if (w & 0xFEFEFEFEu) local |= 2u;
        if ((h0 != 0u && h0 != 0x3F80u) || (h1 != 0u && h1 != 0x3F80u)) local |= 4u;
        if (w == 0x3F803F80u || w == 0x00003F80u) local |= 8u;
        if ((h0 != 0u && h0 != 0x3C00u) || (h1 != 0u && h1 != 0x3C00u)) local |= 16u;
    }
    if (local) atomicOr(&sf, local);
    __syncthreads();
    if (threadIdx.x == 0) flags[0] = sf;
}

__device__ __forceinline__ int mask_mode(unsigned int f) {
    if (!(f & 1u)) return 0;                 // int32 0/1
    if (!(f & 2u)) return 1;                 // uint8 0/1
    if (!(f & 4u)) return (f & 8u) ? 3 : 2;  // bf16 vs f32
    return (!(f & 16u)) ? 3 : 2;             // f16 else f32
}

__device__ __forceinline__ bool mask_bit(int mode, const unsigned int* pmW,
                                         const unsigned char* pm8,
                                         const unsigned short* pm16,
                                         const float* pmf, size_t gi) {
    if (mode == 0) return pmW[gi] != 0u;
    if (mode == 1) return pm8[gi] != 0;
    if (mode == 3) return pm16[gi] != 0;
    return pmf[gi] != 0.0f;
}

// ---------------------------------------------------------------------------
// Diagonal tiles (d=0): triangular 64x64 DP fully in LDS. 4 lanes/cell,
// stride-4 k interleave, shuffle lex-(v,k) reduce. PAD=5 -> conflict-free.
// ---------------------------------------------------------------------------
__global__ __launch_bounds__(256) void fd_diag(
    const float* __restrict__ e_pair, const float* __restrict__ e_unp,
    const unsigned int* __restrict__ pm, const unsigned int* __restrict__ flags,
    float* __restrict__ dp_ws, unsigned short* __restrict__ ptr_ws)
{
    const int b = blockIdx.x / NT_;
    const int I = blockIdx.x % NT_;
    const int t = threadIdx.x;
    const int r0 = I * T_;
    const float* ep = e_pair + (size_t)b * NBUF;
    float* dp = dp_ws + (size_t)b * NBUF;
    unsigned short* ptr = ptr_ws + (size_t)b * NBUF;
    const int mode = mask_mode(flags[0]);
    const unsigned int*   pmW  = pm + (size_t)b * NBUF;
    const unsigned char*  pm8  = ((const unsigned char*) pm) + (size_t)b * NBUF;
    const unsigned short* pm16 = ((const unsigned short*)pm) + (size_t)b * NBUF;
    const float*          pmf  = ((const float*)         pm) + (size_t)b * NBUF;

    __shared__ float Ct[T_][T_ + PAD];
    __shared__ float epl[T_][T_ + PAD];
    __shared__ unsigned char mkb[T_][T_ + PAD];
    __shared__ unsigned short bp[T_][T_ + PAD];
    __shared__ float eu[T_];

    for (int e = t; e < T_ * T_; e += 256) {
        const int r = e >> 6, c = e & 63;
        const size_t gi = (size_t)(r0 + r) * L_ + r0 + c;
        epl[r][c] = ep[gi];
        mkb[r][c] = mask_bit(mode, pmW, pm8, pm16, pmf, gi) ? 1 : 0;
    }
    if (t < T_) eu[t] = e_unp[(size_t)b * L_ + r0 + t];
    __syncthreads();
    if (t < T_) Ct[t][t] = eu[t];
    __syncthreads();

    const int cell = t >> 2, sub = t & 3;
    for (int m = 1; m < T_; ++m) {
        if (cell < T_ - m) {
            const int ti = cell, tj = cell + m;
            float pf_c0 = 0, pf_c1 = 0, pf_in = 0, pf_ep = 0; bool pok = false;
            if (sub == 0) {                               // prefetch epilogue inputs
                pf_c0 = Ct[ti + 1][tj];
                pf_c1 = Ct[ti][tj - 1];
                pf_in = (m >= 2) ? Ct[ti + 1][tj - 1] : 0.0f;
                pf_ep = epl[ti][tj];
                pok = mkb[ti][tj] && (m > 4);
            }
            float mv = INFV; int km = 0;
            for (int tk = ti + sub; tk < tj; tk += 4) {   // ascending k, strict <
                const float v = Ct[ti][tk] + Ct[tk + 1][tj];
                if (v < mv) { mv = v; km = tk; }
            }
            for (int off = 1; off < 4; off <<= 1) {       // lex (v,k) reduce
                const float ov = __shfl_xor(mv, off, 4);
                const int   ok = __shfl_xor(km, off, 4);
                if (ov < mv || (ov == mv && ok < km)) { mv = ov; km = ok; }
            }
            if (sub == 0) {
                const float c0 = pf_c0 + eu[ti];
                const float c1 = pf_c1 + eu[tj];
                const float c2 = pf_in + pf_ep;
                float best = c0; int bv = 0;
                if (c1 < best)        { best = c1; bv = 1; }
                if (pok && c2 < best) { best = c2; bv = 2; }
                if (mv < best)        { best = mv; bv = r0 + km + 3; }
                Ct[ti][tj] = best;
                bp[ti][tj] = (unsigned short)bv;
            }
        }
        __syncthreads();
    }
    for (int e = t; e < T_ * T_; e += 256) {
        const int r = e >> 6, c = e & 63;
        if (c >= r) {
            const size_t gi = (size_t)(r0 + r) * L_ + r0 + c;
            dp[gi] = Ct[r][c];
            if (c > r) ptr[gi] = bp[r][c];
        }
    }
}

// ---------------------------------------------------------------------------
// Off-diagonal tile step (d>=1). Bulk min-plus over interior K blocks
// (4x4 reg tiles), then 127-step intra-tile wavefront: 4 lanes/cell,
// stride-4 k interleave, shuffle lex-(v,k) reduce. PAD=5 conflict-free.
// k ordering left < bulk < right; all merges lex on (v, absolute k)
// == numpy first-occurrence argmin.
// ---------------------------------------------------------------------------
__global__ __launch_bounds__(256) void fd_step(
    const float* __restrict__ e_pair, const float* __restrict__ e_unp,
    const unsigned int* __restrict__ pm, const unsigned int* __restrict__ flags,
    float* __restrict__ dp_ws, unsigned short* __restrict__ ptr_ws,
    int d, int nI)
{
    const int b = blockIdx.x / nI;
    const int I = blockIdx.x % nI;
    const int J = I + d;
    const int t = threadIdx.x;
    const int r0 = I * T_, q0 = J * T_;
    const float* ep = e_pair + (size_t)b * NBUF;
    float* dp = dp_ws + (size_t)b * NBUF;
    unsigned short* ptr = ptr_ws + (size_t)b * NBUF;
    const int mode = mask_mode(flags[0]);
    const unsigned int*   pmW  = pm + (size_t)b * NBUF;
    const unsigned char*  pm8  = ((const unsigned char*) pm) + (size_t)b * NBUF;
    const unsigned short* pm16 = ((const unsigned short*)pm) + (size_t)b * NBUF;
    const float*          pmf  = ((const float*)         pm) + (size_t)b * NBUF;

    __shared__ float WA[T_][T_ + PAD];      // bulk: dp[i][k]; wavefront: tile (I,I)
    __shared__ float WB[T_][T_ + PAD];      // bulk: dp[k+1][j]; wavefront: tile (J,J)
    __shared__ float Ct[T_][T_ + PAD];      // tile being computed
    __shared__ float accv[T_][T_ + PAD];    // bulk lex-min value
    __shared__ unsigned short acck[T_][T_ + PAD];
    __shared__ float epl[T_][T_ + PAD];
    __shared__ unsigned char mkb[T_][T_ + PAD];
    __shared__ unsigned short bp[T_][T_ + PAD];
    __shared__ float euI[T_], euJ[T_], rowB[T_], colL[T_];
    __shared__ float cornerS;

    // ---- bulk: k in [(I+1)T, JT) over interior blocks K ----
    if (d >= 2) {
        float av[16]; int akr[16];
        const int ti0 = (t >> 4) * 4, tj0 = (t & 15) * 4;
#pragma unroll
        for (int q = 0; q < 16; ++q) { av[q] = INFV; akr[q] = 0; }
        for (int K = I + 1; K < J; ++K) {
            const int kb = K * T_;
            __syncthreads();
            for (int e = t; e < T_ * T_; e += 256) {
                const int r = e >> 6, c = e & 63;
                WA[r][c] = dp[(size_t)(r0 + r) * L_ + kb + c];
                WB[r][c] = dp[(size_t)(kb + 1 + r) * L_ + q0 + c];
            }
            __syncthreads();
            for (int kk = 0; kk < T_; ++kk) {
                float a[4], bb[4];
#pragma unroll
                for (int r = 0; r < 4; ++r) a[r] = WA[ti0 + r][kk];
#pragma unroll
                for (int c = 0; c < 4; ++c) bb[c] = WB[kk][tj0 + c];
                const int kg = kb + kk;
#pragma unroll
                for (int r = 0; r < 4; ++r)
#pragma unroll
                    for (int c = 0; c < 4; ++c) {
                        const float v = a[r] + bb[c];
                        const int q = r * 4 + c;
                        if (v < av[q]) { av[q] = v; akr[q] = kg; }   // ascending k
                    }
            }
        }
#pragma unroll
        for (int r = 0; r < 4; ++r)
#pragma unroll
            for (int c = 0; c < 4; ++c) {
                accv[ti0 + r][tj0 + c] = av[r * 4 + c];
                acck[ti0 + r][tj0 + c] = (unsigned short)akr[r * 4 + c];
            }
    }
    __syncthreads();   // protect WA/WB restage

    // ---- stage wavefront inputs ----
    for (int e = t; e < T_ * T_; e += 256) {
        const int r = e >> 6, c = e & 63;
        WA[r][c] = dp[(size_t)(r0 + r) * L_ + r0 + c];   // tile (I,I)
        WB[r][c] = dp[(size_t)(q0 + r) * L_ + q0 + c];   // tile (J,J)
        const size_t gi = (size_t)(r0 + r) * L_ + q0 + c;
        epl[r][c] = ep[gi];
        mkb[r][c] = mask_bit(mode, pmW, pm8, pm16, pmf, gi) ? 1 : 0;
    }
    if (t < T_) {
        euI[t] = e_unp[(size_t)b * L_ + r0 + t];
        euJ[t] = e_unp[(size_t)b * L_ + q0 + t];
        rowB[t] = dp[(size_t)(r0 + T_) * L_ + q0 + t];   // dp[(I+1)T][j]
        colL[t] = dp[(size_t)(r0 + t) * L_ + q0 - 1];    // dp[i][JT-1]
    }
    if (t == 0) cornerS = (d >= 2) ? dp[(size_t)(r0 + T_) * L_ + q0 - 1] : 0.0f;
    __syncthreads();

    // ---- intra-tile wavefront: m = tj - ti, 4 lanes/cell ----
    const int cell = t >> 2, sub = t & 3;
    for (int m = -(T_ - 1); m <= T_ - 1; ++m) {
        const int am = m < 0 ? -m : m;
        if (cell < T_ - am) {
            const int ti = (m < 0) ? cell + am : cell;
            const int tj = ti + m;
            const int span = d * T_ + m;                  // j - i >= 1
            float pf_c0 = 0, pf_c1 = 0, pf_in = 0, pf_ep = 0;
            float bulk_v = INFV; int bulk_k = 0; bool pok = false;
            if (sub == 0) {                               // prefetch epilogue inputs
                pf_c0 = (ti < T_ - 1) ? Ct[ti + 1][tj] : rowB[tj];
                pf_c1 = (tj > 0) ? Ct[ti][tj - 1] : colL[ti];
                if (span == 1)        pf_in = 0.0f;
                else if (ti < T_ - 1) pf_in = (tj > 0) ? Ct[ti + 1][tj - 1] : colL[ti + 1];
                else                  pf_in = (tj > 0) ? rowB[tj - 1] : cornerS;
                pf_ep = epl[ti][tj];
                pok = mkb[ti][tj] && (span > 4);
                if (d >= 2) { bulk_v = accv[ti][tj]; bulk_k = acck[ti][tj]; }
            }
            float mv = INFV; int km = 0;
            // left: k = r0+tk, tk in [ti, T-2] via Ct column; tk = T-1 via rowB
            for (int tk = ti + sub; tk < T_ - 1; tk += 4) {
                const float v = WA[ti][tk] + Ct[tk + 1][tj];
                if (v < mv) { mv = v; km = r0 + tk; }
            }
            if (((T_ - 1 - ti) & 3) == sub) {             // residue-matched lane
                const float v = WA[ti][T_ - 1] + rowB[tj];
                if (v < mv) { mv = v; km = r0 + T_ - 1; }
            }
            // right: k = q0+tk, tk in [0, tj) (all ks > left/bulk ks)
            for (int tk = sub; tk < tj; tk += 4) {
                const float v = Ct[ti][tk] + WB[tk + 1][tj];
                if (v < mv) { mv = v; km = q0 + tk; }
            }
            for (int off = 1; off < 4; off <<= 1) {       // lex (v,k) reduce
                const float ov = __shfl_xor(mv, off, 4);
                const int   ok = __shfl_xor(km, off, 4);
                if (ov < mv || (ov == mv && ok < km)) { mv = ov; km = ok; }
            }
            if (sub == 0) {
                if (bulk_v < mv || (bulk_v == mv && bulk_k < km)) { mv = bulk_v; km = bulk_k; }
                const float c0 = pf_c0 + euI[ti];
                const float c1 = pf_c1 + euJ[tj];
                const float c2 = pf_in + pf_ep;
                float best = c0; int bv = 0;
                if (c1 < best)        { best = c1; bv = 1; }
                if (pok && c2 < best) { best = c2; bv = 2; }
                if (mv < best)        { best = mv; bv = km + 3; }
                Ct[ti][tj] = best;
                bp[ti][tj] = (unsigned short)bv;
            }
        }
        __syncthreads();
    }

    // ---- writeback ----
    for (int e = t; e < T_ * T_; e += 256) {
        const int r = e >> 6, c = e & 63;
        dp [(size_t)(r0 + r) * L_ + q0 + c] = Ct[r][c];
        ptr[(size_t)(r0 + r) * L_ + q0 + c] = bp[r][c];
    }
}

// ---------------------------------------------------------------------------
// Backtrace: warm this batch's 512KB ptr slab into the local XCD L2, then
// serial LIFO walk (t==0) with L2-hit latency.
// ---------------------------------------------------------------------------
__global__ __launch_bounds__(256) void fd_backtrace(
    const unsigned short* __restrict__ ptr_ws, int* __restrict__ out)
{
    const int b = blockIdx.x;
    const int t = threadIdx.x;
    const unsigned short* ptr = ptr_ws + (size_t)b * NBUF;
    int* res = out + (size_t)b * L_;
    __shared__ int sti[2 * L_], stj[2 * L_];

    const uint4* p4 = (const uint4*)ptr;           // 512KB = 32768 uint4
    unsigned int acc = 0;
    for (int idx = t; idx < NBUF / 8; idx += 256) {
        const uint4 v = p4[idx];
        acc += v.x ^ v.y ^ v.z ^ v.w;
    }
    asm volatile("" :: "v"(acc));                  // keep warm loads live
    for (int idx = t; idx < L_; idx += 256) res[idx] = -1;
    __syncthreads();

    if (t == 0) {
        int sp = 1; sti[0] = 0; stj[0] = L_ - 1;
        while (sp > 0) {
            --sp;
            const int i = sti[sp], j = stj[sp];
            if (i < j) {
                const int p = (int)ptr[(size_t)i * L_ + j];
                if (p == 0)      { sti[sp] = i + 1; stj[sp] = j;     ++sp; }
                else if (p == 1) { sti[sp] = i;     stj[sp] = j - 1; ++sp; }
                else if (p == 2) {
                    res[i] = j; res[j] = i;
                    if (i + 1 <= j - 1) { sti[sp] = i + 1; stj[sp] = j - 1; ++sp; }
                } else {
                    const int k = p - 3;
                    sti[sp] = i;     stj[sp] = k; ++sp;   // pushed first
                    sti[sp] = k + 1; stj[sp] = j; ++sp;   // popped first (matches ref)
                }
            }
        }
    }
}

extern "C" void kernel_launch(void* const* d_in, const int* in_sizes, int n_in,
                              void* d_out, int out_size, void* d_ws, size_t ws_size,
                              hipStream_t stream) {
    const float* e_pair = (const float*)d_in[0];
    const float* e_unp  = (const float*)d_in[1];
    const unsigned int* pm = (const unsigned int*)d_in[2];
    const int B = in_sizes[1] / L_;
    int* out = (int*)d_out;

    // ws layout: [flags: 256B] [dp: B*L*L f32] [ptr: B*L*L u16]
    unsigned int* flags = (unsigned int*)d_ws;
    float* dp_ws = (float*)((char*)d_ws + 256);
    unsigned short* ptr_ws = (unsigned short*)(dp_ws + (size_t)B * NBUF);

    const int n32 = in_sizes[2] / 4;
    fd_mask_probe<<<dim3(1), dim3(1024), 0, stream>>>(pm, n32, flags);
    fd_diag<<<dim3(B * NT_), dim3(256), 0, stream>>>(e_pair, e_unp, pm, flags,
                                                     dp_ws, ptr_ws);
    for (int d = 1; d < NT_; ++d) {
        const int nI = NT_ - d;
        fd_step<<<dim3(B * nI), dim3(256), 0, stream>>>(e_pair, e_unp, pm, flags,
                                                        dp_ws, ptr_ws, d, nI);
    }
    fd_backtrace<<<dim3(B), dim3(256), 0, stream>>>(ptr_ws, out);
}